// Round 2
// baseline (677.837 us; speedup 1.0000x reference)
//
#include <hip/hip_runtime.h>
#include <hip/hip_bf16.h>

#define NEG_VAL -1000000000.0f

// Kernel 1: per-node partial dot products.
// a[n] = dot(h[n], W[0:128])   (n as dest)
// c[n] = dot(h[n], W[128:256]) (n as source)
// One 64-lane wave per node, float2 loads, butterfly shuffle reduce.
__global__ void node_dots(const float* __restrict__ h,
                          const float* __restrict__ W,
                          float* __restrict__ a,
                          float* __restrict__ c,
                          int N) {
    int gid  = blockIdx.x * blockDim.x + threadIdx.x;
    int node = gid >> 6;
    int lane = threadIdx.x & 63;
    if (node >= N) return;

    const float2* h2 = (const float2*)(h + (size_t)node * 128);
    float2 v  = h2[lane];
    float2 wd = ((const float2*)W)[lane];
    float2 ws = ((const float2*)(W + 128))[lane];

    float sd = v.x * wd.x + v.y * wd.y;
    float ss = v.x * ws.x + v.y * ws.y;

    #pragma unroll
    for (int off = 32; off; off >>= 1) {
        sd += __shfl_xor(sd, off, 64);
        ss += __shfl_xor(ss, off, 64);
    }
    if (lane == 0) {
        a[node] = sd;
        c[node] = ss;
    }
}

// Kernel 2: NEG fill, grid-stride float4 loop so block-dispatch overhead
// amortizes (R1 lesson: 147K single-store blocks were dispatch-bound).
__global__ void fill_neg(float4* __restrict__ out, long long n4) {
    const float4 v = make_float4(NEG_VAL, NEG_VAL, NEG_VAL, NEG_VAL);
    long long stride = (long long)gridDim.x * blockDim.x;
    for (long long i = (long long)blockIdx.x * blockDim.x + threadIdx.x;
         i < n4; i += stride) {
        out[i] = v;
    }
}

// Kernel 3: per-edge scatter of the linear-layer output.
__global__ void edge_scatter(const int* __restrict__ src,
                             const int* __restrict__ dst,
                             const float* __restrict__ wgt,
                             const float* __restrict__ a,
                             const float* __restrict__ c,
                             const float* __restrict__ W,
                             const float* __restrict__ b,
                             float* __restrict__ out,
                             int E, int N) {
    int e = blockIdx.x * blockDim.x + threadIdx.x;
    if (e >= E) return;
    int s = src[e];
    int d = dst[e];
    float val = a[d] + c[s] + wgt[e] * W[256] + b[0];
    out[(size_t)d * N + s] = val;
}

extern "C" void kernel_launch(void* const* d_in, const int* in_sizes, int n_in,
                              void* d_out, int out_size, void* d_ws, size_t ws_size,
                              hipStream_t stream) {
    const float* h       = (const float*)d_in[0];  // [N, 128]
    const int*   sources = (const int*)d_in[1];    // [E]
    const int*   dests   = (const int*)d_in[2];    // [E]
    const float* weights = (const float*)d_in[3];  // [E]
    const float* W       = (const float*)d_in[4];  // [257]
    const float* b       = (const float*)d_in[5];  // [1]
    float* out = (float*)d_out;                    // [N, N]

    const int N = in_sizes[0] / 128;               // 12288
    const int E = in_sizes[1];                     // 393216

    float* a = (float*)d_ws;                       // [N]
    float* c = a + N;                              // [N]

    // 1) per-node dots: one wave per node, 4 waves per 256-thread block
    {
        int waves_per_block = 256 / 64;
        int blocks = (N + waves_per_block - 1) / waves_per_block;
        node_dots<<<blocks, 256, 0, stream>>>(h, W, a, c, N);
    }

    // 2) NEG fill: 4096 blocks x 256 threads, grid-stride float4
    {
        long long n4 = (long long)out_size / 4;
        fill_neg<<<4096, 256, 0, stream>>>((float4*)out, n4);
    }

    // 3) scatter edge values
    {
        int blocks = (E + 255) / 256;
        edge_scatter<<<blocks, 256, 0, stream>>>(sources, dests, weights, a, c, W, b,
                                                 out, E, N);
    }
}

// Round 3
// 673.279 us; speedup vs baseline: 1.0068x; 1.0068x over previous
//
#include <hip/hip_runtime.h>
#include <hip/hip_bf16.h>

#define NEG_VAL -1000000000.0f
#define ROW_N 12288   // N is fixed for this problem; LDS row buffer is sized to it

// Kernel 1: per-node partial dot products + zero the bucket counters.
// a[n] = dot(h[n], W[0:128]); c[n] = dot(h[n], W[128:256]).
// One 64-lane wave per node; lane 0 also zeroes counts[n]/cursor[n].
__global__ void node_dots(const float* __restrict__ h,
                          const float* __restrict__ W,
                          float* __restrict__ a,
                          float* __restrict__ c,
                          int* __restrict__ counts,
                          int* __restrict__ cursor,
                          int N) {
    int gid  = blockIdx.x * blockDim.x + threadIdx.x;
    int node = gid >> 6;
    int lane = threadIdx.x & 63;
    if (node >= N) return;

    const float2* h2 = (const float2*)(h + (size_t)node * 128);
    float2 v  = h2[lane];
    float2 wd = ((const float2*)W)[lane];
    float2 ws = ((const float2*)(W + 128))[lane];

    float sd = v.x * wd.x + v.y * wd.y;
    float ss = v.x * ws.x + v.y * ws.y;

    #pragma unroll
    for (int off = 32; off; off >>= 1) {
        sd += __shfl_xor(sd, off, 64);
        ss += __shfl_xor(ss, off, 64);
    }
    if (lane == 0) {
        a[node]      = sd;
        c[node]      = ss;
        counts[node] = 0;
        cursor[node] = 0;
    }
}

// Kernel 2: histogram of dests.
__global__ void hist_dest(const int* __restrict__ dst, int* __restrict__ counts, int E) {
    int e = blockIdx.x * blockDim.x + threadIdx.x;
    if (e < E) atomicAdd(&counts[dst[e]], 1);
}

// Kernel 3: exclusive scan of counts -> offsets. Single block, 256 threads,
// N/256 entries per thread (serial chunk scan + LDS Hillis-Steele on sums).
__global__ void scan_counts(const int* __restrict__ counts,
                            int* __restrict__ offsets, int N) {
    __shared__ int sums[256];
    int tid = threadIdx.x;
    int per = N / 256;            // 48
    int base = tid * per;
    int s = 0;
    for (int i = 0; i < per; i++) s += counts[base + i];
    sums[tid] = s;
    __syncthreads();
    for (int off = 1; off < 256; off <<= 1) {
        int t = (tid >= off) ? sums[tid - off] : 0;
        __syncthreads();
        sums[tid] += t;
        __syncthreads();
    }
    int run = (tid == 0) ? 0 : sums[tid - 1];
    for (int i = 0; i < per; i++) {
        offsets[base + i] = run;
        run += counts[base + i];
    }
}

// Kernel 4: bucket edges by dest, computing the linear-layer value inline.
__global__ void bucket_edges(const int* __restrict__ src,
                             const int* __restrict__ dst,
                             const float* __restrict__ wgt,
                             const float* __restrict__ a,
                             const float* __restrict__ c,
                             const float* __restrict__ W,
                             const float* __restrict__ b,
                             const int* __restrict__ offsets,
                             int* __restrict__ cursor,
                             int* __restrict__ edge_s,
                             float* __restrict__ edge_v,
                             int E) {
    int e = blockIdx.x * blockDim.x + threadIdx.x;
    if (e >= E) return;
    int s = src[e];
    int d = dst[e];
    int pos = offsets[d] + atomicAdd(&cursor[d], 1);
    edge_s[pos] = s;
    edge_v[pos] = a[d] + c[s] + wgt[e] * W[256] + b[0];
}

// Kernel 5: one block per output row. Build the row in LDS (NEG fill + edge
// overwrites), then stream to global once, fully coalesced. Output bytes are
// written exactly once -> HBM write-minimal.
__global__ __launch_bounds__(256) void row_fill(const int* __restrict__ offsets,
                                                const int* __restrict__ counts,
                                                const int* __restrict__ edge_s,
                                                const float* __restrict__ edge_v,
                                                float* __restrict__ out) {
    __shared__ float row[ROW_N];           // 48 KB
    int d = blockIdx.x;
    int t = threadIdx.x;
    float4* r4 = (float4*)row;
    const float4 negv = make_float4(NEG_VAL, NEG_VAL, NEG_VAL, NEG_VAL);
    #pragma unroll
    for (int i = 0; i < ROW_N / 4 / 256; i++)   // 12 iterations
        r4[t + 256 * i] = negv;
    __syncthreads();

    int beg = offsets[d];
    int cnt = counts[d];
    for (int i = t; i < cnt; i += 256)
        row[edge_s[beg + i]] = edge_v[beg + i];
    __syncthreads();

    float4* o4 = (float4*)(out + (size_t)d * ROW_N);
    #pragma unroll
    for (int i = 0; i < ROW_N / 4 / 256; i++)
        o4[t + 256 * i] = r4[t + 256 * i];
}

extern "C" void kernel_launch(void* const* d_in, const int* in_sizes, int n_in,
                              void* d_out, int out_size, void* d_ws, size_t ws_size,
                              hipStream_t stream) {
    const float* h       = (const float*)d_in[0];  // [N, 128]
    const int*   sources = (const int*)d_in[1];    // [E]
    const int*   dests   = (const int*)d_in[2];    // [E]
    const float* weights = (const float*)d_in[3];  // [E]
    const float* W       = (const float*)d_in[4];  // [257]
    const float* b       = (const float*)d_in[5];  // [1]
    float* out = (float*)d_out;                    // [N, N]

    const int N = in_sizes[0] / 128;               // 12288
    const int E = in_sizes[1];                     // 393216

    // workspace layout (floats then ints), ~3.4 MB total
    float* a      = (float*)d_ws;          // [N]
    float* c      = a + N;                 // [N]
    float* edge_v = c + N;                 // [E]
    int*   counts = (int*)(edge_v + E);    // [N]
    int*   cursor = counts + N;            // [N]
    int*   offs   = cursor + N;            // [N]
    int*   edge_s = offs + N;              // [E]

    // 1) per-node dots + zero counters (one wave per node)
    {
        int waves_per_block = 256 / 64;
        int blocks = (N + waves_per_block - 1) / waves_per_block;
        node_dots<<<blocks, 256, 0, stream>>>(h, W, a, c, counts, cursor, N);
    }
    // 2) histogram of dests
    hist_dest<<<(E + 255) / 256, 256, 0, stream>>>(dests, counts, E);
    // 3) scan -> start offsets
    scan_counts<<<1, 256, 0, stream>>>(counts, offs, N);
    // 4) bucket edges by dest (computes vals inline)
    bucket_edges<<<(E + 255) / 256, 256, 0, stream>>>(sources, dests, weights,
                                                      a, c, W, b, offs, cursor,
                                                      edge_s, edge_v, E);
    // 5) one block per row: LDS-staged single-pass output write
    row_fill<<<N, 256, 0, stream>>>(offs, counts, edge_s, edge_v, out);
}

// Round 5
// 641.197 us; speedup vs baseline: 1.0571x; 1.0500x over previous
//
#include <hip/hip_runtime.h>
#include <hip/hip_bf16.h>

#define NEG_VAL -1000000000.0f
#define ROW_N 12288        // N fixed for this problem
#define HALF_N 6144        // row split across 2 blocks
#define CAP 128            // per-row edge bucket capacity (Poisson(32); >128 is ~11 sigma)

typedef float vf4 __attribute__((ext_vector_type(4)));   // clang-native, OK for nontemporal builtin

// Kernel 1: per-node partial dot products + zero the bucket counters.
// a[n] = dot(h[n], W[0:128]); c[n] = dot(h[n], W[128:256]).
__global__ void node_dots(const float* __restrict__ h,
                          const float* __restrict__ W,
                          float* __restrict__ a,
                          float* __restrict__ c,
                          int* __restrict__ cnt,
                          int N) {
    int gid  = blockIdx.x * blockDim.x + threadIdx.x;
    int node = gid >> 6;
    int lane = threadIdx.x & 63;
    if (node >= N) return;

    const float2* h2 = (const float2*)(h + (size_t)node * 128);
    float2 v  = h2[lane];
    float2 wd = ((const float2*)W)[lane];
    float2 ws = ((const float2*)(W + 128))[lane];

    float sd = v.x * wd.x + v.y * wd.y;
    float ss = v.x * ws.x + v.y * ws.y;

    #pragma unroll
    for (int off = 32; off; off >>= 1) {
        sd += __shfl_xor(sd, off, 64);
        ss += __shfl_xor(ss, off, 64);
    }
    if (lane == 0) {
        a[node]   = sd;
        c[node]   = ss;
        cnt[node] = 0;
    }
}

// Kernel 2: direct bucketing — per edge, grab a slot in the dest row's
// fixed-capacity bucket and store (source, value). No hist/scan pass.
__global__ void bucket_edges(const int* __restrict__ src,
                             const int* __restrict__ dst,
                             const float* __restrict__ wgt,
                             const float* __restrict__ a,
                             const float* __restrict__ c,
                             const float* __restrict__ W,
                             const float* __restrict__ b,
                             int* __restrict__ cnt,
                             int* __restrict__ edge_s,
                             float* __restrict__ edge_v,
                             int E) {
    int e = blockIdx.x * blockDim.x + threadIdx.x;
    if (e >= E) return;
    int s = src[e];
    int d = dst[e];
    int pos = atomicAdd(&cnt[d], 1);
    if (pos < CAP) {   // statistically never exceeded; clamp prevents corruption
        size_t slot = (size_t)d * CAP + pos;
        edge_s[slot] = s;
        edge_v[slot] = a[d] + c[s] + wgt[e] * W[256] + b[0];
    }
}

// Kernel 3: two blocks per output row (half-row each, 24 KB LDS -> 6 blocks/CU,
// 24 waves/CU). Build half-row in LDS, apply this half's edges, stream out
// once with nontemporal float4 stores. Output bytes written exactly once.
__global__ __launch_bounds__(256) void row_fill(const int* __restrict__ cnt,
                                                const int* __restrict__ edge_s,
                                                const float* __restrict__ edge_v,
                                                float* __restrict__ out) {
    __shared__ float row[HALF_N];          // 24 KB
    int d    = blockIdx.x >> 1;
    int base = (blockIdx.x & 1) * HALF_N;
    int t    = threadIdx.x;

    vf4* r4 = (vf4*)row;
    const vf4 negv = {NEG_VAL, NEG_VAL, NEG_VAL, NEG_VAL};
    #pragma unroll
    for (int i = 0; i < HALF_N / 4 / 256; i++)   // 6 iterations
        r4[t + 256 * i] = negv;
    __syncthreads();

    int n = cnt[d];
    if (n > CAP) n = CAP;
    const int*   es = edge_s + (size_t)d * CAP;
    const float* ev = edge_v + (size_t)d * CAP;
    for (int i = t; i < n; i += 256) {
        int col = es[i] - base;
        if ((unsigned)col < (unsigned)HALF_N) row[col] = ev[i];
    }
    __syncthreads();

    vf4* o4 = (vf4*)(out + (size_t)d * ROW_N + base);
    #pragma unroll
    for (int i = 0; i < HALF_N / 4 / 256; i++)
        __builtin_nontemporal_store(r4[t + 256 * i], &o4[t + 256 * i]);
}

extern "C" void kernel_launch(void* const* d_in, const int* in_sizes, int n_in,
                              void* d_out, int out_size, void* d_ws, size_t ws_size,
                              hipStream_t stream) {
    const float* h       = (const float*)d_in[0];  // [N, 128]
    const int*   sources = (const int*)d_in[1];    // [E]
    const int*   dests   = (const int*)d_in[2];    // [E]
    const float* weights = (const float*)d_in[3];  // [E]
    const float* W       = (const float*)d_in[4];  // [257]
    const float* b       = (const float*)d_in[5];  // [1]
    float* out = (float*)d_out;                    // [N, N]

    const int N = in_sizes[0] / 128;               // 12288
    const int E = in_sizes[1];                     // 393216

    // workspace layout (~12.7 MB)
    float* a      = (float*)d_ws;                   // [N]
    float* c      = a + N;                          // [N]
    float* edge_v = c + N;                          // [N*CAP]
    int*   cnt    = (int*)(edge_v + (size_t)N * CAP);  // [N]
    int*   edge_s = cnt + N;                        // [N*CAP]

    // 1) per-node dots + zero counters (one wave per node)
    node_dots<<<(N * 64 + 255) / 256, 256, 0, stream>>>(h, W, a, c, cnt, N);

    // 2) direct bucket by dest (computes edge values inline)
    bucket_edges<<<(E + 255) / 256, 256, 0, stream>>>(sources, dests, weights,
                                                      a, c, W, b, cnt,
                                                      edge_s, edge_v, E);

    // 3) half-row LDS staging, single coalesced nontemporal write pass
    row_fill<<<2 * N, 256, 0, stream>>>(cnt, edge_s, edge_v, out);
}